// Round 8
// baseline (154.916 us; speedup 1.0000x reference)
//
#include <hip/hip_runtime.h>
#include <math.h>

#define S_LEN 1024
#define EPS 1e-6f

typedef __attribute__((ext_vector_type(8)))  short bf16x8;
typedef __attribute__((ext_vector_type(4)))  short bf16x4;
typedef __attribute__((ext_vector_type(16))) float float16v;

// Workspace layout (bytes):
//   kcnt2  : int  [32*64*32]      @ 0          (262144)  [bh][dim][seg]
//   qcnt2  : int  [32*64*32]      @ 262144     (262144)  [bh][dim][seg]
//   klist2 : ushort [2048*1024]   @ 524288     (4194304) [(bh,dim)][seg*32+pos]
//   qpair  : uint [2048*1024]     @ 4718592    (8388608) packed (w18|rank4|s10)
//   --- scatter extension (ws_size >= 64004096) ---
//   qflag  : uchar [32768]        @ 30416896   (32768)   1 = tie row (atomic path)
//   Obuf   : ushort [32768*8*64]  @ 30449664   (33554432) bf16 rank-slot rows
// R8: k_mainB restructured to attention form: O_q = sum_s v_s (k_s.q),
// den_q = z.q.  S^T = mfma(K,Q) (K-dim=64), scale w/den, pack -> P,
// O^T = mfma(V^T,P) (K-dim = nm, chunked by 32).  The explicit M build
// (2 staged RTs + 256 VALU FMA/thread) is gone; fragment index expressions
// are carried over verbatim from the R7-verified kernel.

// lgkm-only barrier: __syncthreads() would force vmcnt(0), draining in-flight
// global stores/atomics + prefetch loads. Intra-block hazards here are
// LDS-only; global loads are register-consumed (compiler inserts counted
// vmcnt); stores/atomics are never read back in-kernel.
__device__ __forceinline__ void bar_lgkm() {
    asm volatile("s_waitcnt lgkmcnt(0)" ::: "memory");
    __builtin_amdgcn_s_barrier();
    __builtin_amdgcn_sched_barrier(0);
    asm volatile("" ::: "memory");
}

// VGPR anchor (rule #17): forces materialization at this program point
// (defeats load-sinking; R3 k_pre VGPR=20 showed loads sunk into loops).
#define PIN(x) asm volatile("" : "+v"(x))

__device__ __forceinline__ unsigned short f2bf(float f) {
    unsigned int u = __float_as_uint(f);
    unsigned int r = (u + 0x7fffu + ((u >> 16) & 1u)) >> 16;
    return (unsigned short)r;
}

__device__ __forceinline__ bf16x8 pack8(float4 a, float4 b) {
    bf16x8 r;
    r[0] = (short)f2bf(a.x); r[1] = (short)f2bf(a.y);
    r[2] = (short)f2bf(a.z); r[3] = (short)f2bf(a.w);
    r[4] = (short)f2bf(b.x); r[5] = (short)f2bf(b.y);
    r[6] = (short)f2bf(b.z); r[7] = (short)f2bf(b.w);
    return r;
}

// 1024 blocks = (bh, seg), 512 threads = 8 waves x 4 positions. (unchanged)
__global__ __launch_bounds__(512) void k_pre(const float* __restrict__ keys,
                                             const float* __restrict__ queries,
                                             int* __restrict__ kcnt2,
                                             unsigned short* __restrict__ klist2,
                                             int* __restrict__ qcnt2,
                                             unsigned* __restrict__ qpair,
                                             unsigned char* __restrict__ qflag,
                                             float* __restrict__ out) {
    const int bh   = blockIdx.x >> 5;
    const int blk  = blockIdx.x & 31;          // segment id
    const int wv   = threadIdx.x >> 6;         // 0..7
    const int lane = threadIdx.x & 63;

    __shared__ int khist[64], qhist[64];
    __shared__ alignas(16) unsigned rq_s[8][4][64];   // 8 KB: per-wave row stage
    if (threadIdx.x < 64) { khist[threadIdx.x] = 0; qhist[threadIdx.x] = 0; }
    __syncthreads();

    const int s0 = blk * 32 + wv * 4;
    float kv[4], qv[4];
    #pragma unroll
    for (int i = 0; i < 4; ++i) {              // all loads issued up-front
        kv[i] = keys   [((size_t)bh * 1024 + s0 + i) * 64 + lane];
        qv[i] = queries[((size_t)bh * 1024 + s0 + i) * 64 + lane];
    }

    // zero d_out slice (independent store, issues inside the load shadow)
    {
        float4 zz = {0.f, 0.f, 0.f, 0.f};
        float4* po = (float4*)(out + (size_t)blockIdx.x * 2048);
        po[threadIdx.x] = zz;
    }

    // anchor: one vmcnt wait for all 8 loads; compute below is register/LDS
    #pragma unroll
    for (int i = 0; i < 4; ++i) { PIN(kv[i]); PIN(qv[i]); }

    // stage |q| bits to LDS (wave-private rows)
    unsigned ud[4];
    #pragma unroll
    for (int i = 0; i < 4; ++i) {
        ud[i] = __float_as_uint(qv[i]) & 0x7fffffffu;
        rq_s[wv][i][lane] = ud[i];
    }

    // ---- keys: 4 interleaved wave-argmaxes ----
    float bv[4]; int bi[4];
    #pragma unroll
    for (int i = 0; i < 4; ++i) { bv[i] = fabsf(kv[i]); bi[i] = lane; }
    #pragma unroll
    for (int off = 1; off < 64; off <<= 1) {
        #pragma unroll
        for (int i = 0; i < 4; ++i) {
            float ov = __shfl_xor(bv[i], off, 64);
            int   oi = __shfl_xor(bi[i], off, 64);
            if (ov > bv[i] || (ov == bv[i] && oi < bi[i])) { bv[i] = ov; bi[i] = oi; }
        }
    }
    #pragma unroll
    for (int i = 0; i < 4; ++i) {
        if (lane == 0) {
            int pos = atomicAdd(&khist[bi[i]], 1);
            klist2[((size_t)bh * 64 + bi[i]) * 1024 + blk * 32 + pos] =
                (unsigned short)(s0 + i);
        }
    }

    // ---- queries: rank via LDS uint4 broadcast (same-addr, conflict-free) ----
    int gt[4] = {0, 0, 0, 0};
    #pragma unroll
    for (int k4 = 0; k4 < 16; ++k4) {
        #pragma unroll
        for (int i = 0; i < 4; ++i) {
            const uint4 vv = *(const uint4*)&rq_s[wv][i][k4 * 4];
            gt[i] += (vv.x > ud[i]) ? 1 : 0;
            gt[i] += (vv.y > ud[i]) ? 1 : 0;
            gt[i] += (vv.z > ud[i]) ? 1 : 0;
            gt[i] += (vv.w > ud[i]) ? 1 : 0;
        }
    }
    int S[4];                                  // permutation check for ties
    #pragma unroll
    for (int i = 0; i < 4; ++i) S[i] = gt[i];
    #pragma unroll
    for (int off = 1; off < 64; off <<= 1) {
        #pragma unroll
        for (int i = 0; i < 4; ++i) S[i] += __shfl_xor(S[i], off, 64);
    }
    float e[4];
    #pragma unroll
    for (int i = 0; i < 4; ++i) e[i] = expf(__uint_as_float(ud[i]));
    int copies[4], contrib[4], rank[4];
    #pragma unroll
    for (int i = 0; i < 4; ++i) {
        if (S[i] == 2016) {                    // no ties (wave-uniform branch)
            contrib[i] = (gt[i] < 8);
            copies[i]  = contrib[i] ? 2 : 0;
            rank[i]    = gt[i];                // unique slot 0..7
        } else {                               // exact tie handling (rare)
            int eq = 0, eql = 0;
            #pragma unroll
            for (int k = 0; k < 64; ++k) {
                unsigned ui = (unsigned)__builtin_amdgcn_readlane((int)ud[i], k);
                eq  += (ui == ud[i]) ? 1 : 0;
                eql += (ui == ud[i] && k < lane) ? 1 : 0;
            }
            int pos_low  = 2 * gt[i] + eql;
            int pos_high = pos_low + eq;       // eq includes self
            copies[i]  = (pos_low < 16 ? 1 : 0) + (pos_high < 16 ? 1 : 0);
            contrib[i] = (pos_low < 16);
            rank[i]    = 15;                   // sentinel -> atomic path
        }
    }
    float ce[4];
    #pragma unroll
    for (int i = 0; i < 4; ++i) ce[i] = (float)copies[i] * e[i];
    #pragma unroll
    for (int off = 1; off < 64; off <<= 1) {
        #pragma unroll
        for (int i = 0; i < 4; ++i) ce[i] += __shfl_xor(ce[i], off, 64);
    }
    #pragma unroll
    for (int i = 0; i < 4; ++i) {
        if (contrib[i]) {
            int pos = atomicAdd(&qhist[lane], 1);
            unsigned wb = __float_as_uint(e[i] / ce[i]) & 0xFFFFC000u;  // 18-bit w
            qpair[((size_t)bh * 64 + lane) * 1024 + blk * 32 + pos] =
                wb | ((unsigned)rank[i] << 10) | (unsigned)(s0 + i);
        }
        if (qflag && lane == 0)
            qflag[bh * 1024 + s0 + i] = (S[i] == 2016) ? 0 : 1;
    }
    __syncthreads();
    if (threadIdx.x < 64) {                    // transposed [bh][dim][seg]
        kcnt2[(bh * 64 + threadIdx.x) * 32 + blk] = khist[threadIdx.x];
        qcnt2[(bh * 64 + threadIdx.x) * 32 + blk] = qhist[threadIdx.x];
    }
}

// 2048 blocks = (bh, bank). Attention-form (R8): no M build.  Phases:
// scan -> gather lists -> z (f32 exact) -> stage K(swz bf16)+V^T(bf16,pad40)
// -> per 128-query megabatch: {flush prev | stage Q(swz, union w/ O^T)+den(dbl)
// | S^T=mfma(K,Q) -> scale w/den -> P | O^T+=mfma(VT,P) | epilogue -> QO}.
// SC: flush -> rank-addressed Obuf slots; rank-15 ties -> atomics.
template <bool SC>
__global__ __launch_bounds__(256) void k_mainB(const float* __restrict__ keys,
                                               const float* __restrict__ values,
                                               const float* __restrict__ queries,
                                               const int* __restrict__ kcnt2,
                                               const unsigned short* __restrict__ klist2,
                                               const int* __restrict__ qcnt2,
                                               const unsigned* __restrict__ qpair,
                                               unsigned short* __restrict__ Obuf,
                                               float* __restrict__ out) {
    const int g     = blockIdx.x;      // 0..2047 = (bh, bank)
    const int bh    = g >> 6;
    const int bank  = g & 63;
    const int t     = threadIdx.x;
    const int lane  = t & 63;
    const int grp   = t >> 6;
    const int hi    = lane >> 5;
    const int l31   = lane & 31;

    __shared__ alignas(16) unsigned short K_bf[32 * 64];    // 4 KB   swizzled K
    __shared__ alignas(16) unsigned short VT_bf[64 * 40];   // 5 KB   V^T, pad 40
    __shared__ alignas(16) unsigned short QO[128 * 72];     // 18 KB  Q(swz) U O^T
    __shared__ alignas(16) unsigned short P_bf[128 * 40];   // 10 KB  P, pad 40 (alias zp4)
    __shared__ unsigned short s_match[256];
    __shared__ unsigned q_ent[256];
    __shared__ int    koffs_s[33], qoffs_s[33];
    __shared__ float  z_s[64];
    __shared__ double den_s[128];
    __shared__ float  w_s[128];
    __shared__ int    sq_s[128];

    // dual prefix scan (contiguous transposed counts)
    if (t < 64) {
        int i = t & 31;
        int c = (t < 32) ? kcnt2[(bh * 64 + bank) * 32 + i]
                         : qcnt2[(bh * 64 + bank) * 32 + i];
        #pragma unroll
        for (int off = 1; off < 32; off <<= 1) {
            int o = __shfl(c, t - off, 64);
            if (i >= off) c += o;
        }
        if (t < 32) { if (i == 0) koffs_s[0] = 0; koffs_s[i + 1] = c; }
        else        { if (i == 0) qoffs_s[0] = 0; qoffs_s[i + 1] = c; }
    }
    bar_lgkm();

    const int nq = qoffs_s[32];
    const int nm = koffs_s[32];
    if (nq == 0) return;
    const size_t listbase = (size_t)(bh * 64 + bank) * 1024;
    if (nm == 0) {
        if constexpr (SC) {        // zero-fill owned Obuf slots
            for (int jg = t; jg < nq; jg += 256) {
                int seg = 0;
                #pragma unroll
                for (int i = 1; i < 32; ++i) if (jg >= qoffs_s[i]) seg = i;
                unsigned e = qpair[listbase + seg * 32 + (jg - qoffs_s[seg])];
                int r = (e >> 10) & 15;
                if (r < 8) {
                    uint4 z4 = {0u, 0u, 0u, 0u};
                    uint4* dst = (uint4*)&Obuf[(((size_t)bh * 1024 +
                                 (e & 1023u)) * 8 + r) * 64];
                    #pragma unroll
                    for (int x = 0; x < 8; ++x) dst[x] = z4;
                }
            }
        }
        return;
    }

    const float* kb = keys    + (size_t)bh * S_LEN * 64;
    const float* vb = values  + (size_t)bh * S_LEN * 64;
    const float* qb = queries + (size_t)bh * S_LEN * 64;

    // ---- gather window 0 of both lists together (one RT) ----
    if (t < min(256, nm)) {
        int seg = 0;
        #pragma unroll
        for (int i = 1; i < 32; ++i) if (t >= koffs_s[i]) seg = i;
        s_match[t] = klist2[listbase + seg * 32 + (t - koffs_s[seg])];
    }
    if (t < min(256, nq)) {
        int seg = 0;
        #pragma unroll
        for (int i = 1; i < 32; ++i) if (t >= qoffs_s[i]) seg = i;
        q_ent[t] = qpair[listbase + seg * 32 + (t - qoffs_s[seg])];
    }
    bar_lgkm();

    int win = 0;                               // current s_match window base

    // ---- z[dk] = sum_s K[s][dk] in f32 (exact; coalesced row reads) ----
    {
        float* zp4 = (float*)P_bf;             // alias: P not yet live
        float zp = 0.f;
        for (int cb = 0; cb < nm; cb += 256) {
            int cn = min(256, nm - cb);
            if (cb > 0) {                      // refill window (nm>256: ~never)
                bar_lgkm();
                if (t < cn) {
                    int idx = cb + t, seg = 0;
                    #pragma unroll
                    for (int i = 1; i < 32; ++i) if (idx >= koffs_s[i]) seg = i;
                    s_match[t] = klist2[listbase + seg * 32 + (idx - koffs_s[seg])];
                }
                bar_lgkm();
                win = cb;
            }
            for (int r = grp; r < cn; r += 4)
                zp += kb[(size_t)s_match[r] * 64 + lane];
        }
        zp4[grp * 64 + lane] = zp;
        bar_lgkm();
        if (t < 64) z_s[t] = zp4[t] + zp4[64 + t] + zp4[128 + t] + zp4[192 + t];
    }

    const int kchunks = (nm + 31) >> 5;

    // ensure s_match window covers chunk starting at c0
    auto ensure_win = [&](int c0) {
        int need = c0 & ~255;
        if (need != win) {
            bar_lgkm();
            int cn = min(256, nm - need);
            if (t < cn) {
                int idx = need + t, seg = 0;
                #pragma unroll
                for (int i = 1; i < 32; ++i) if (idx >= koffs_s[i]) seg = i;
                s_match[t] = klist2[listbase + seg * 32 + (idx - koffs_s[seg])];
            }
            bar_lgkm();
            win = need;
        }
    };

    // stage 32-key chunk kc: K_bf (bf16, old-M swizzle) + VT_bf (transposed V).
    // rows >= cnt zero-filled (S rows / VT cols beyond nm become 0).
    auto stage_kv = [&](int kc) {
        int c0 = kc * 32, cnt = min(32, nm - c0);
        int r = t >> 3, c8 = t & 7;            // 32 rows x 8 col-octets
        float4 ka = {0,0,0,0}, ka2 = {0,0,0,0}, va = {0,0,0,0}, va2 = {0,0,0,0};
        if (r < cnt) {
            int s = s_match[(c0 - win) + r];
            const float4* ks = (const float4*)(kb + (size_t)s * 64 + c8 * 8);
            ka = ks[0]; ka2 = ks[1];
            const float4* vs = (const float4*)(vb + (size_t)s * 64 + c8 * 8);
            va = vs[0]; va2 = vs[1];
        }
        *(bf16x8*)&K_bf[r * 64 + ((c8 ^ (r & 7)) << 3)] = pack8(ka, ka2);
        VT_bf[(c8 * 8 + 0) * 40 + r] = f2bf(va.x);
        VT_bf[(c8 * 8 + 1) * 40 + r] = f2bf(va.y);
        VT_bf[(c8 * 8 + 2) * 40 + r] = f2bf(va.z);
        VT_bf[(c8 * 8 + 3) * 40 + r] = f2bf(va.w);
        VT_bf[(c8 * 8 + 4) * 40 + r] = f2bf(va2.x);
        VT_bf[(c8 * 8 + 5) * 40 + r] = f2bf(va2.y);
        VT_bf[(c8 * 8 + 6) * 40 + r] = f2bf(va2.z);
        VT_bf[(c8 * 8 + 7) * 40 + r] = f2bf(va2.w);
    };

    if (kchunks == 1) { ensure_win(0); stage_kv(0); }
    bar_lgkm();                                // z_s (+ K/VT if single-chunk)

    const int qn_ = grp * 32 + l31;            // this lane's q (S col, P row, O col)

    int prev_nb = 0;
    for (int qb0 = 0, batch = 0; qb0 < nq; qb0 += 128, ++batch) {
        const int nb = min(128, nq - qb0);

        if (qb0 != 0 && (qb0 & 255) == 0) {    // refill q_ent (nq>256: ~never)
            bar_lgkm();
            if (qb0 + t < nq) {
                int jg = qb0 + t, seg = 0;
                #pragma unroll
                for (int i = 1; i < 32; ++i) if (jg >= qoffs_s[i]) seg = i;
                q_ent[t] = qpair[listbase + seg * 32 + (jg - qoffs_s[seg])];
            }
            bar_lgkm();
        }

        // flush previous batch's O^T rows (QO) before stage overwrites QO
        if (batch > 0) {
            float* ob = out + (size_t)bh * S_LEN * 64;
            unsigned short* obuf_b = SC ? Obuf + (size_t)bh * 1024 * 512 : nullptr;
            #pragma unroll
            for (int jj = 0; jj < 32; ++jj) {
                int j = grp * 32 + jj;
                if (j < prev_nb) {
                    unsigned short vb16 = QO[j * 72 + lane];
                    int sr = sq_s[j];
                    int s  = sr & 1023;
                    if constexpr (SC) {
                        int r = (sr >> 10) & 15;
                        if (r < 8)
                            obuf_b[((size_t)s * 8 + r) * 64 + lane] = vb16;
                        else
                            unsafeAtomicAdd(&ob[(size_t)s * 64 + lane],
                                __uint_as_float((unsigned)vb16 << 16));
                    } else {
                        unsafeAtomicAdd(&ob[(size_t)s * 64 + lane],
                            __uint_as_float((unsigned)vb16 << 16));
                    }
                }
            }
            bar_lgkm();                        // QO reads done before re-stage
        }

        // ---- stage Q (bf16, swizzled, rows>=nb zeroed) + den (double) ----
        #pragma unroll
        for (int h = 0; h < 2; ++h) {
            int j = h * 64 + (t >> 2), cq = t & 3;
            bf16x8 p0 = {}, p1 = {};
            double d = 0.0;
            if (j < nb) {
                unsigned e = q_ent[(qb0 + j) & 255];
                if ((t & 3) == 0) {
                    sq_s[j] = (int)(e & 0x3FFFu);          // s | rank<<10
                    w_s[j]  = __uint_as_float(e & 0xFFFFC000u);
                }
                const float4* src =
                    (const float4*)(qb + (size_t)(e & 1023u) * 64 + cq * 16);
                float4 f0 = src[0], f1 = src[1], f2 = src[2], f3 = src[3];
                p0 = pack8(f0, f1);
                p1 = pack8(f2, f3);
                const float4* zz4 = (const float4*)&z_s[cq * 16];
                float4 z0 = zz4[0], z1 = zz4[1], z2 = zz4[2], z3 = zz4[3];
                double da, db;
                da  = (double)z0.x * f0.x + (double)z0.y * f0.y + (double)z0.z * f0.z + (double)z0.w * f0.w;
                db  = (double)z1.x * f1.x + (double)z1.y * f1.y + (double)z1.z * f1.z + (double)z1.w * f1.w;
                da += (double)z2.x * f2.x + (double)z2.y * f2.y + (double)z2.z * f2.z + (double)z2.w * f2.w;
                db += (double)z3.x * f3.x + (double)z3.y * f3.y + (double)z3.z * f3.z + (double)z3.w * f3.w;
                d = da + db;
            }
            int c0 = cq * 2;
            *(bf16x8*)&QO[j * 72 + ((c0 ^ (j & 7)) << 3)]       = p0;
            *(bf16x8*)&QO[j * 72 + (((c0 + 1) ^ (j & 7)) << 3)] = p1;
            d += __shfl_xor(d, 1, 64);
            d += __shfl_xor(d, 2, 64);
            if ((t & 3) == 0) den_s[j] = d;
        }
        bar_lgkm();                            // Q/den staged

        float16v C0, C1;                       // O^T accumulators (2 dv-tiles)
        #pragma unroll
        for (int i = 0; i < 16; ++i) { C0[i] = 0.f; C1[i] = 0.f; }

        for (int kc = 0; kc < kchunks; ++kc) {
            if (kchunks > 1) {                 // rare: restage per chunk
                bar_lgkm();                    // prev chunk's K/VT reads done
                ensure_win(kc * 32);
                stage_kv(kc);
                bar_lgkm();
            }
            // S^T tile: D[s][q] = sum_d K[s][d] * Q[q][d]
            float16v Sv;
            #pragma unroll
            for (int i = 0; i < 16; ++i) Sv[i] = 0.f;
            #pragma unroll
            for (int ks = 0; ks < 4; ++ks) {
                int ch = ks * 2 + hi;
                bf16x8 af = *(const bf16x8*)&K_bf[l31 * 64 + ((ch ^ (l31 & 7)) << 3)];
                bf16x8 bf = *(const bf16x8*)&QO[qn_ * 72 + ((ch ^ (qn_ & 7)) << 3)];
                Sv = __builtin_amdgcn_mfma_f32_32x32x16_bf16(af, bf, Sv, 0, 0, 0);
            }
            // scale by w/den (per-lane q = qn_), pack -> P rows (s-index = C row)
            {
                double den = den_s[qn_];
                float  w   = w_s[qn_];
                float rinv = (float)((double)w / (den + (double)EPS));
                #pragma unroll
                for (int rq = 0; rq < 4; ++rq) {
                    bf16x4 pk;
                    pk[0] = (short)f2bf(Sv[rq * 4 + 0] * rinv);
                    pk[1] = (short)f2bf(Sv[rq * 4 + 1] * rinv);
                    pk[2] = (short)f2bf(Sv[rq * 4 + 2] * rinv);
                    pk[3] = (short)f2bf(Sv[rq * 4 + 3] * rinv);
                    *(bf16x4*)&P_bf[qn_ * 40 + rq * 8 + hi * 4] = pk;
                }
            }
            bar_lgkm();                        // P visible
            // O^T += V^T x P : D[dv][q] = sum_s VT[dv][s] * P[q][s]
            #pragma unroll
            for (int ks2 = 0; ks2 < 2; ++ks2) {
                int ch2 = ks2 * 2 + hi;
                bf16x8 pf  = *(const bf16x8*)&P_bf[qn_ * 40 + ch2 * 8];
                bf16x8 af0 = *(const bf16x8*)&VT_bf[l31 * 40 + ch2 * 8];
                C0 = __builtin_amdgcn_mfma_f32_32x32x16_bf16(af0, pf, C0, 0, 0, 0);
                bf16x8 af1 = *(const bf16x8*)&VT_bf[(32 + l31) * 40 + ch2 * 8];
                C1 = __builtin_amdgcn_mfma_f32_32x32x16_bf16(af1, pf, C1, 0, 0, 0);
            }
        }

        // epilogue: O^T[q = qn_][dv] -> QO rows (old verified write pattern)
        #pragma unroll
        for (int rq = 0; rq < 4; ++rq) {
            bf16x4 pk0, pk1;
            pk0[0] = (short)f2bf(C0[rq * 4 + 0]);
            pk0[1] = (short)f2bf(C0[rq * 4 + 1]);
            pk0[2] = (short)f2bf(C0[rq * 4 + 2]);
            pk0[3] = (short)f2bf(C0[rq * 4 + 3]);
            *(bf16x4*)&QO[qn_ * 72 + rq * 8 + hi * 4] = pk0;
            pk1[0] = (short)f2bf(C1[rq * 4 + 0]);
            pk1[1] = (short)f2bf(C1[rq * 4 + 1]);
            pk1[2] = (short)f2bf(C1[rq * 4 + 2]);
            pk1[3] = (short)f2bf(C1[rq * 4 + 3]);
            *(bf16x4*)&QO[qn_ * 72 + 32 + rq * 8 + hi * 4] = pk1;
        }
        bar_lgkm();                            // O^T ready for flush
        prev_nb = nb;
    }

    // final flush
    {
        float* ob = out + (size_t)bh * S_LEN * 64;
        unsigned short* obuf_b = SC ? Obuf + (size_t)bh * 1024 * 512 : nullptr;
        #pragma unroll
        for (int jj = 0; jj < 32; ++jj) {
            int j = grp * 32 + jj;
            if (j < prev_nb) {
                unsigned short vb16 = QO[j * 72 + lane];
                int sr = sq_s[j];
                int s  = sr & 1023;
                if constexpr (SC) {
                    int r = (sr >> 10) & 15;
                    if (r < 8)
                        obuf_b[((size_t)s * 8 + r) * 64 + lane] = vb16;
                    else
                        unsafeAtomicAdd(&ob[(size_t)s * 64 + lane],
                            __uint_as_float((unsigned)vb16 << 16));
                } else {
                    unsafeAtomicAdd(&ob[(size_t)s * 64 + lane],
                        __uint_as_float((unsigned)vb16 << 16));
                }
            }
        }
    }
}

// 1024 blocks x 4 waves x 8 queries: sum the 8 rank slots per no-tie query
// (coalesced 128B reads) -> out. Tie rows (qflag) already accumulated via
// atomics onto k_pre's zeroed out.
__global__ __launch_bounds__(256) void k_reduce(const unsigned short* __restrict__ Obuf,
                                                const unsigned char* __restrict__ qflag,
                                                float* __restrict__ out) {
    const int wv   = threadIdx.x >> 6;
    const int lane = threadIdx.x & 63;
    const int q0   = (blockIdx.x * 4 + wv) * 8;
    #pragma unroll
    for (int i = 0; i < 8; ++i) {
        int q = q0 + i;
        if (qflag[q]) continue;                // atomic-accumulated row
        const unsigned short* obr = Obuf + (size_t)q * 512;
        float acc = 0.f;
        #pragma unroll
        for (int r = 0; r < 8; ++r)
            acc += __uint_as_float((unsigned)obr[r * 64 + lane] << 16);
        out[(size_t)q * 64 + lane] = acc;
    }
}

extern "C" void kernel_launch(void* const* d_in, const int* in_sizes, int n_in,
                              void* d_out, int out_size, void* d_ws, size_t ws_size,
                              hipStream_t stream) {
    const float* keys    = (const float*)d_in[0];
    const float* values  = (const float*)d_in[1];
    const float* queries = (const float*)d_in[2];
    char* ws = (char*)d_ws;
    int*            kcnt2  = (int*)(ws);
    int*            qcnt2  = (int*)(ws + 262144);
    unsigned short* klist2 = (unsigned short*)(ws + 524288);
    unsigned*       qpair  = (unsigned*)(ws + 4718592);
    unsigned char*  qflag  = (unsigned char*)(ws + 30416896);
    unsigned short* Obuf   = (unsigned short*)(ws + 30449664);
    const bool big2 = (ws_size >= 64004096u);

    k_pre<<<1024, 512, 0, stream>>>(keys, queries, kcnt2, klist2, qcnt2, qpair,
                                    big2 ? qflag : nullptr, (float*)d_out);
    if (big2) {
        k_mainB<true><<<2048, 256, 0, stream>>>(keys, values, queries, kcnt2,
                                                klist2, qcnt2, qpair, Obuf,
                                                (float*)d_out);
        k_reduce<<<1024, 256, 0, stream>>>(Obuf, qflag, (float*)d_out);
    } else {
        k_mainB<false><<<2048, 256, 0, stream>>>(keys, values, queries, kcnt2,
                                                 klist2, qcnt2, qpair, Obuf,
                                                 (float*)d_out);
    }
}

// Round 9
// 143.942 us; speedup vs baseline: 1.0762x; 1.0762x over previous
//
#include <hip/hip_runtime.h>
#include <math.h>

#define S_LEN 1024
#define EPS 1e-6f

typedef __attribute__((ext_vector_type(8)))  short bf16x8;
typedef __attribute__((ext_vector_type(4)))  short bf16x4;
typedef __attribute__((ext_vector_type(16))) float float16v;

// Workspace layout (bytes):
//   kcnt2  : int  [32*64*32]      @ 0          (262144)  [bh][dim][seg]
//   qcnt2  : int  [32*64*32]      @ 262144     (262144)  [bh][dim][seg]
//   klist2 : ushort [2048*1024]   @ 524288     (4194304) [(bh,dim)][seg*32+pos]
//   qpair  : uint [2048*1024]     @ 4718592    (8388608) packed (w18|rank4|s10)
//   --- scatter extension (ws_size >= 64004096) ---
//   qflag  : uchar [32768]        @ 30416896   (32768)   1 = tie row (atomic path)
//   Obuf   : ushort [32768*8*64]  @ 30449664   (33554432) bf16 rank-slot rows
// R9: k_mainB = R7-verified structure, but the M-build reads k/v DIRECTLY
// from global (no LDS staging, no per-8-key barriers): k-row is a coalesced
// 256B wave read, v-slice is wave-uniform 64B (HW broadcast, 1 line). All
// keys independent -> 2-deep software pipeline (PIN-anchored per R4 lesson)
// exposes ~1 RT total, vs 2 RTs + 3 barriers per 8 keys in R7. R8's
// attention-form rewrite is reverted (regressed: 42.5KB LDS -> occ 17%,
// 4.2x bank conflicts).

// lgkm-only barrier: __syncthreads() would force vmcnt(0), draining in-flight
// global stores/atomics + prefetch loads. Intra-block hazards here are
// LDS-only; global loads are register-consumed (compiler inserts counted
// vmcnt); stores/atomics are never read back in-kernel.
__device__ __forceinline__ void bar_lgkm() {
    asm volatile("s_waitcnt lgkmcnt(0)" ::: "memory");
    __builtin_amdgcn_s_barrier();
    __builtin_amdgcn_sched_barrier(0);
    asm volatile("" ::: "memory");
}

// VGPR anchor (rule #17): forces materialization at this program point
// (defeats load-sinking; R3 k_pre VGPR=20 showed loads sunk into loops).
#define PIN(x) asm volatile("" : "+v"(x))

__device__ __forceinline__ unsigned short f2bf(float f) {
    unsigned int u = __float_as_uint(f);
    unsigned int r = (u + 0x7fffu + ((u >> 16) & 1u)) >> 16;
    return (unsigned short)r;
}

__device__ __forceinline__ bf16x8 pack8(float4 a, float4 b) {
    bf16x8 r;
    r[0] = (short)f2bf(a.x); r[1] = (short)f2bf(a.y);
    r[2] = (short)f2bf(a.z); r[3] = (short)f2bf(a.w);
    r[4] = (short)f2bf(b.x); r[5] = (short)f2bf(b.y);
    r[6] = (short)f2bf(b.z); r[7] = (short)f2bf(b.w);
    return r;
}

// 1024 blocks = (bh, seg), 512 threads = 8 waves x 4 positions. (R7 verbatim)
__global__ __launch_bounds__(512) void k_pre(const float* __restrict__ keys,
                                             const float* __restrict__ queries,
                                             int* __restrict__ kcnt2,
                                             unsigned short* __restrict__ klist2,
                                             int* __restrict__ qcnt2,
                                             unsigned* __restrict__ qpair,
                                             unsigned char* __restrict__ qflag,
                                             float* __restrict__ out) {
    const int bh   = blockIdx.x >> 5;
    const int blk  = blockIdx.x & 31;          // segment id
    const int wv   = threadIdx.x >> 6;         // 0..7
    const int lane = threadIdx.x & 63;

    __shared__ int khist[64], qhist[64];
    __shared__ alignas(16) unsigned rq_s[8][4][64];   // 8 KB: per-wave row stage
    if (threadIdx.x < 64) { khist[threadIdx.x] = 0; qhist[threadIdx.x] = 0; }
    __syncthreads();

    const int s0 = blk * 32 + wv * 4;
    float kv[4], qv[4];
    #pragma unroll
    for (int i = 0; i < 4; ++i) {              // all loads issued up-front
        kv[i] = keys   [((size_t)bh * 1024 + s0 + i) * 64 + lane];
        qv[i] = queries[((size_t)bh * 1024 + s0 + i) * 64 + lane];
    }

    // zero d_out slice (independent store, issues inside the load shadow)
    {
        float4 zz = {0.f, 0.f, 0.f, 0.f};
        float4* po = (float4*)(out + (size_t)blockIdx.x * 2048);
        po[threadIdx.x] = zz;
    }

    // anchor: one vmcnt wait for all 8 loads; compute below is register/LDS
    #pragma unroll
    for (int i = 0; i < 4; ++i) { PIN(kv[i]); PIN(qv[i]); }

    // stage |q| bits to LDS (wave-private rows)
    unsigned ud[4];
    #pragma unroll
    for (int i = 0; i < 4; ++i) {
        ud[i] = __float_as_uint(qv[i]) & 0x7fffffffu;
        rq_s[wv][i][lane] = ud[i];
    }

    // ---- keys: 4 interleaved wave-argmaxes ----
    float bv[4]; int bi[4];
    #pragma unroll
    for (int i = 0; i < 4; ++i) { bv[i] = fabsf(kv[i]); bi[i] = lane; }
    #pragma unroll
    for (int off = 1; off < 64; off <<= 1) {
        #pragma unroll
        for (int i = 0; i < 4; ++i) {
            float ov = __shfl_xor(bv[i], off, 64);
            int   oi = __shfl_xor(bi[i], off, 64);
            if (ov > bv[i] || (ov == bv[i] && oi < bi[i])) { bv[i] = ov; bi[i] = oi; }
        }
    }
    #pragma unroll
    for (int i = 0; i < 4; ++i) {
        if (lane == 0) {
            int pos = atomicAdd(&khist[bi[i]], 1);
            klist2[((size_t)bh * 64 + bi[i]) * 1024 + blk * 32 + pos] =
                (unsigned short)(s0 + i);
        }
    }

    // ---- queries: rank via LDS uint4 broadcast (same-addr, conflict-free) ----
    int gt[4] = {0, 0, 0, 0};
    #pragma unroll
    for (int k4 = 0; k4 < 16; ++k4) {
        #pragma unroll
        for (int i = 0; i < 4; ++i) {
            const uint4 vv = *(const uint4*)&rq_s[wv][i][k4 * 4];
            gt[i] += (vv.x > ud[i]) ? 1 : 0;
            gt[i] += (vv.y > ud[i]) ? 1 : 0;
            gt[i] += (vv.z > ud[i]) ? 1 : 0;
            gt[i] += (vv.w > ud[i]) ? 1 : 0;
        }
    }
    int S[4];                                  // permutation check for ties
    #pragma unroll
    for (int i = 0; i < 4; ++i) S[i] = gt[i];
    #pragma unroll
    for (int off = 1; off < 64; off <<= 1) {
        #pragma unroll
        for (int i = 0; i < 4; ++i) S[i] += __shfl_xor(S[i], off, 64);
    }
    float e[4];
    #pragma unroll
    for (int i = 0; i < 4; ++i) e[i] = expf(__uint_as_float(ud[i]));
    int copies[4], contrib[4], rank[4];
    #pragma unroll
    for (int i = 0; i < 4; ++i) {
        if (S[i] == 2016) {                    // no ties (wave-uniform branch)
            contrib[i] = (gt[i] < 8);
            copies[i]  = contrib[i] ? 2 : 0;
            rank[i]    = gt[i];                // unique slot 0..7
        } else {                               // exact tie handling (rare)
            int eq = 0, eql = 0;
            #pragma unroll
            for (int k = 0; k < 64; ++k) {
                unsigned ui = (unsigned)__builtin_amdgcn_readlane((int)ud[i], k);
                eq  += (ui == ud[i]) ? 1 : 0;
                eql += (ui == ud[i] && k < lane) ? 1 : 0;
            }
            int pos_low  = 2 * gt[i] + eql;
            int pos_high = pos_low + eq;       // eq includes self
            copies[i]  = (pos_low < 16 ? 1 : 0) + (pos_high < 16 ? 1 : 0);
            contrib[i] = (pos_low < 16);
            rank[i]    = 15;                   // sentinel -> atomic path
        }
    }
    float ce[4];
    #pragma unroll
    for (int i = 0; i < 4; ++i) ce[i] = (float)copies[i] * e[i];
    #pragma unroll
    for (int off = 1; off < 64; off <<= 1) {
        #pragma unroll
        for (int i = 0; i < 4; ++i) ce[i] += __shfl_xor(ce[i], off, 64);
    }
    #pragma unroll
    for (int i = 0; i < 4; ++i) {
        if (contrib[i]) {
            int pos = atomicAdd(&qhist[lane], 1);
            unsigned wb = __float_as_uint(e[i] / ce[i]) & 0xFFFFC000u;  // 18-bit w
            qpair[((size_t)bh * 64 + lane) * 1024 + blk * 32 + pos] =
                wb | ((unsigned)rank[i] << 10) | (unsigned)(s0 + i);
        }
        if (qflag && lane == 0)
            qflag[bh * 1024 + s0 + i] = (S[i] == 2016) ? 0 : 1;
    }
    __syncthreads();
    if (threadIdx.x < 64) {                    // transposed [bh][dim][seg]
        kcnt2[(bh * 64 + threadIdx.x) * 32 + blk] = khist[threadIdx.x];
        qcnt2[(bh * 64 + threadIdx.x) * 32 + blk] = qhist[threadIdx.x];
    }
}

// 2048 blocks = (bh, bank), fused build + query (R7 structure). R9: build
// reads k/v directly from global, 2-deep pipelined, ZERO build barriers.
// SC: flush -> rank-addressed Obuf slots (plain stores); rank-15 ties ->
// atomics; k_reduce sums.
template <bool SC>
__global__ __launch_bounds__(256) void k_mainB(const float* __restrict__ keys,
                                               const float* __restrict__ values,
                                               const float* __restrict__ queries,
                                               const int* __restrict__ kcnt2,
                                               const unsigned short* __restrict__ klist2,
                                               const int* __restrict__ qcnt2,
                                               const unsigned* __restrict__ qpair,
                                               unsigned short* __restrict__ Obuf,
                                               float* __restrict__ out) {
    const int g     = blockIdx.x;      // 0..2047 = (bh, bank)
    const int bh    = g >> 6;
    const int bank  = g & 63;
    const int t     = threadIdx.x;
    const int lane  = t & 63;
    const int grp   = t >> 6;

    __shared__ alignas(16) unsigned short M_bf[64 * 64];   // 8 KB
    __shared__ alignas(16) unsigned short Q_bf[64 * 64];   // 8 KB
    __shared__ alignas(16) unsigned short Ou_bf[64 * 68];  // 8.7 KB (O^T)
    __shared__ unsigned short s_match[256];
    __shared__ unsigned q_ent[256];
    __shared__ int    koffs_s[33], qoffs_s[33];
    __shared__ float  z_s[64];
    __shared__ double den_s[64];
    __shared__ float  w_s[2][64];
    __shared__ int    sq_s[2][64];

    // dual prefix scan: lanes 0-31 keys, 32-63 queries (contiguous counts)
    if (t < 64) {
        int i = t & 31;
        int c = (t < 32) ? kcnt2[(bh * 64 + bank) * 32 + i]
                         : qcnt2[(bh * 64 + bank) * 32 + i];
        #pragma unroll
        for (int off = 1; off < 32; off <<= 1) {
            int o = __shfl(c, t - off, 64);    // guarded by i >= off
            if (i >= off) c += o;
        }
        if (t < 32) { if (i == 0) koffs_s[0] = 0; koffs_s[i + 1] = c; }
        else        { if (i == 0) qoffs_s[0] = 0; qoffs_s[i + 1] = c; }
    }
    bar_lgkm();

    const int nq = qoffs_s[32];
    const int nm = koffs_s[32];
    if (nq == 0) return;
    const size_t listbase = (size_t)(bh * 64 + bank) * 1024;
    if (nm == 0) {
        // SC: empty bank still owns Obuf slots for its entries -> zero-fill
        if constexpr (SC) {
            for (int jg = t; jg < nq; jg += 256) {
                int seg = 0;
                #pragma unroll
                for (int i = 1; i < 32; ++i) if (jg >= qoffs_s[i]) seg = i;
                unsigned e = qpair[listbase + seg * 32 + (jg - qoffs_s[seg])];
                int r = (e >> 10) & 15;
                if (r < 8) {
                    uint4 z4 = {0u, 0u, 0u, 0u};
                    uint4* dst = (uint4*)&Obuf[(((size_t)bh * 1024 +
                                 (e & 1023u)) * 8 + r) * 64];
                    #pragma unroll
                    for (int x = 0; x < 8; ++x) dst[x] = z4;
                }
            }
        }
        return;
    }

    // ---- phase 2: both chunk-0 gathers issued together (one bar) ----
    {
        if (t < min(256, nm)) {                // klist chunk 0
            int seg = 0;
            #pragma unroll
            for (int i = 1; i < 32; ++i) if (t >= koffs_s[i]) seg = i;
            s_match[t] = klist2[listbase + seg * 32 + (t - koffs_s[seg])];
        }
        if (t < min(256, nq)) {                // q_ent chunk 0 (hides under build)
            int seg = 0;
            #pragma unroll
            for (int i = 1; i < 32; ++i) if (t >= qoffs_s[i]) seg = i;
            q_ent[t] = qpair[listbase + seg * 32 + (t - qoffs_s[seg])];
        }
    }
    bar_lgkm();

    // ---- build M[dv][dk] = sum_s v[s][dv]*k[s][dk], z[dk] = sum_s k[s][dk]
    // R9: direct global loads, 2-deep pipeline, no barriers.
    //   k-read: kb[s*64+lane]        -> 256B coalesced per wave
    //   v-read: vb[s*64+grp*16 ..15] -> wave-uniform 64B (HW broadcast)
    {
        float acc[16];
        #pragma unroll
        for (int m = 0; m < 16; ++m) acc[m] = 0.f;
        float zacc = 0.f;                      // every wave computes full z
        const float* kb = keys   + (size_t)bh * S_LEN * 64;
        const float* vb = values + (size_t)bh * S_LEN * 64;
        for (int cb = 0; cb < nm; cb += 256) {
            const int cn = min(256, nm - cb);
            if (cb > 0) {                      // refill window (nm>256: ~never)
                bar_lgkm();                    // prev window reads done
                if (t < cn) {
                    int idx = cb + t, seg = 0;
                    #pragma unroll
                    for (int i = 1; i < 32; ++i) if (idx >= koffs_s[i]) seg = i;
                    s_match[t] = klist2[listbase + seg * 32 + (idx - koffs_s[seg])];
                }
                bar_lgkm();
            }
            // preload key 0
            float kcur; float4 v0c, v1c, v2c, v3c;
            {
                int s = s_match[0];
                kcur = kb[(size_t)s * 64 + lane];
                const float4* vp = (const float4*)(vb + (size_t)s * 64 + grp * 16);
                v0c = vp[0]; v1c = vp[1]; v2c = vp[2]; v3c = vp[3];
            }
            for (int r = 0; r < cn; ++r) {
                const bool more = (r + 1 < cn);
                float kn = 0.f;
                float4 v0n = {0,0,0,0}, v1n = {0,0,0,0},
                       v2n = {0,0,0,0}, v3n = {0,0,0,0};
                if (more) {                    // issue next key's loads NOW
                    int s = s_match[r + 1];
                    kn = kb[(size_t)s * 64 + lane];
                    const float4* vp = (const float4*)(vb + (size_t)s * 64 + grp * 16);
                    v0n = vp[0]; v1n = vp[1]; v2n = vp[2]; v3n = vp[3];
                    // anchor: keep the loads issued here, not sunk past compute
                    PIN(kn);
                    PIN(v0n.x); PIN(v0n.y); PIN(v0n.z); PIN(v0n.w);
                    PIN(v1n.x); PIN(v1n.y); PIN(v1n.z); PIN(v1n.w);
                    PIN(v2n.x); PIN(v2n.y); PIN(v2n.z); PIN(v2n.w);
                    PIN(v3n.x); PIN(v3n.y); PIN(v3n.z); PIN(v3n.w);
                }
                zacc += kcur;
                acc[ 0] += v0c.x * kcur; acc[ 1] += v0c.y * kcur;
                acc[ 2] += v0c.z * kcur; acc[ 3] += v0c.w * kcur;
                acc[ 4] += v1c.x * kcur; acc[ 5] += v1c.y * kcur;
                acc[ 6] += v1c.z * kcur; acc[ 7] += v1c.w * kcur;
                acc[ 8] += v2c.x * kcur; acc[ 9] += v2c.y * kcur;
                acc[10] += v2c.z * kcur; acc[11] += v2c.w * kcur;
                acc[12] += v3c.x * kcur; acc[13] += v3c.y * kcur;
                acc[14] += v3c.z * kcur; acc[15] += v3c.w * kcur;
                if (!more) break;
                kcur = kn; v0c = v0n; v1c = v1n; v2c = v2n; v3c = v3n;
            }
        }
        // write M as bf16, row-major [dv][dk], 16B-chunk XOR swizzle
        #pragma unroll
        for (int m = 0; m < 16; ++m) {
            int dv = grp * 16 + m;
            M_bf[dv * 64 + (((lane >> 3) ^ (dv & 7)) << 3) + (lane & 7)] = f2bf(acc[m]);
        }
        if (t < 64) z_s[t] = zacc;             // wave 0 holds the full sum
    }
    bar_lgkm();                        // M_bf/z_s visible (q_ent already is)

    // ---- query loop over [0, nq): pipelined + prefetched (R7 verbatim) ----
    const float* qb = queries + (size_t)bh * S_LEN * 64;
    float*       ob = out     + (size_t)bh * S_LEN * 64;
    unsigned short* obuf_b = SC ? Obuf + (size_t)bh * 1024 * 512 : nullptr;
    const int dvh = grp >> 1, jh = grp & 1;            // wave's 32x32 tile
    const int hi  = lane >> 5;
    const int jq  = t >> 2, cq = t & 3;                // stage mapping

    int prev_nb = 0;
    bool have_pf = false;                              // next-batch q row in regs
    float4 f0, f1, f2, f3;
    unsigned pe = 0;
    for (int qloc = 0, batch = 0; qloc < nq; qloc += 64, ++batch) {
        const int nb  = min(64, nq - qloc);
        const int cur = batch & 1;

        if (qloc != 0 && (qloc & 255) == 0) {  // refill q_ent past chunk 0
            if (qloc + t < nq) {
                int jg = qloc + t;
                int seg = 0;
                #pragma unroll
                for (int i = 1; i < 32; ++i) if (jg >= qoffs_s[i]) seg = i;
                q_ent[t] = qpair[listbase + seg * 32 + (jg - qoffs_s[seg])];
            }
            bar_lgkm();
        }

        // A1: entry + cold q loads issued FIRST (don't queue behind stores)
        unsigned e = 0;
        const bool act = (jq < nb);
        if (act) {
            e = have_pf ? pe : q_ent[(qloc & 255) + jq];
            if (!have_pf) {
                const float4* src =
                    (const float4*)(qb + (size_t)(e & 1023u) * 64 + cq * 16);
                f0 = src[0]; f1 = src[1]; f2 = src[2]; f3 = src[3];
            }
        }

        // A2: flush previous batch (SC: plain bf16 stores to rank slots;
        // rank-15 tie entries keep atomic add; fire-and-forget either way)
        if (batch > 0) {
            #pragma unroll
            for (int jj = 0; jj < 16; ++jj) {
                int j = grp * 16 + jj;
                if (j < prev_nb) {
                    unsigned short vb16 = Ou_bf[j * 68 + lane];
                    int sr = sq_s[1 - cur][j];
                    int s  = sr & 1023;
                    if constexpr (SC) {
                        int r = (sr >> 10) & 15;
                        if (r < 8)
                            obuf_b[((size_t)s * 8 + r) * 64 + lane] = vb16;
                        else
                            unsafeAtomicAdd(&ob[(size_t)s * 64 + lane],
                                __uint_as_float((unsigned)vb16 << 16));
                    } else {
                        unsafeAtomicAdd(&ob[(size_t)s * 64 + lane],
                            __uint_as_float((unsigned)vb16 << 16));
                    }
                }
            }
        }

        // A3: pack + denominator + LDS stage
        {
            bf16x8 p0 = {}, p1 = {};
            double d = 0.0;
            if (act) {
                if ((t & 3) == 0) {
                    sq_s[cur][jq] = (int)(e & 0x3FFFu);        // s | rank<<10
                    w_s[cur][jq]  = __uint_as_float(e & 0xFFFFC000u);
                }
                p0 = pack8(f0, f1);
                p1 = pack8(f2, f3);
                const float4* zz4 = (const float4*)&z_s[cq * 16];
                float4 z0 = zz4[0], z1 = zz4[1], z2 = zz4[2], z3 = zz4[3];
                double da, db;
                da  = (double)z0.x * f0.x + (double)z0.y * f0.y + (double)z0.z * f0.z + (double)z0.w * f0.w;
                db  = (double)z1.x * f1.x + (double)z1.y * f1.y + (double)z1.z * f1.z + (double)z1.w * f1.w;
                da += (double)z2.x * f2.x + (double)z2.y * f2.y + (double)z2.z * f2.z + (double)z2.w * f2.w;
                db += (double)z3.x * f3.x + (double)z3.y * f3.y + (double)z3.z * f3.z + (double)z3.w * f3.w;
                d = da + db;
            }
            int c0 = cq * 2;
            *(bf16x8*)&Q_bf[jq * 64 + ((c0 ^ (jq & 7)) << 3)]       = p0;
            *(bf16x8*)&Q_bf[jq * 64 + (((c0 + 1) ^ (jq & 7)) << 3)] = p1;
            d += __shfl_xor(d, 1, 64);
            d += __shfl_xor(d, 2, 64);
            if ((t & 3) == 0) den_s[jq] = d;
        }

        // A4: prefetch next batch's q row into registers (same chunk only)
        {
            const int qn = qloc + 64;
            have_pf = false;
            if (qn < nq && (qn & 255) != 0) {
                int nbn = min(64, nq - qn);
                if (jq < nbn) {
                    pe = q_ent[(qn & 255) + jq];
                    const float4* src =
                        (const float4*)(qb + (size_t)(pe & 1023u) * 64 + cq * 16);
                    f0 = src[0]; f1 = src[1]; f2 = src[2]; f3 = src[3];
                    have_pf = true;
                }
            }
        }
        bar_lgkm();                    // (C) staged; prev Ou_bf reads complete

        // MFMA: O[dv][j] = sum_dk M[dv][dk] * Q[j][dk]
        float16v C;
        #pragma unroll
        for (int i = 0; i < 16; ++i) C[i] = 0.f;
        const int am = dvh * 32 + (lane & 31);
        const int bn = jh  * 32 + (lane & 31);
        #pragma unroll
        for (int ks = 0; ks < 4; ++ks) {
            int ch = ks * 2 + hi;
            bf16x8 af = *(const bf16x8*)&M_bf[am * 64 + ((ch ^ (am & 7)) << 3)];
            bf16x8 bf = *(const bf16x8*)&Q_bf[bn * 64 + ((ch ^ (bn & 7)) << 3)];
            C = __builtin_amdgcn_mfma_f32_32x32x16_bf16(af, bf, C, 0, 0, 0);
        }
        // epilogue: scale by w/den, write O^T[j=bn][dv] as bf16
        {
            double den = den_s[bn];
            float  w   = w_s[cur][bn];
            float rinv = (float)((double)w / (den + (double)EPS));
            #pragma unroll
            for (int rq = 0; rq < 4; ++rq) {
                bf16x4 pk;
                pk[0] = (short)f2bf(C[rq * 4 + 0] * rinv);
                pk[1] = (short)f2bf(C[rq * 4 + 1] * rinv);
                pk[2] = (short)f2bf(C[rq * 4 + 2] * rinv);
                pk[3] = (short)f2bf(C[rq * 4 + 3] * rinv);
                *(bf16x4*)&Ou_bf[bn * 68 + dvh * 32 + rq * 8 + hi * 4] = pk;
            }
        }
        bar_lgkm();                    // (D) O ready; Q_bf reads complete
        prev_nb = nb;
    }
    // final flush
    {
        const int cur = (((nq + 63) >> 6) - 1) & 1;    // parity of last batch
        #pragma unroll
        for (int jj = 0; jj < 16; ++jj) {
            int j = grp * 16 + jj;
            if (j < prev_nb) {
                unsigned short vb16 = Ou_bf[j * 68 + lane];
                int sr = sq_s[cur][j];
                int s  = sr & 1023;
                if constexpr (SC) {
                    int r = (sr >> 10) & 15;
                    if (r < 8)
                        obuf_b[((size_t)s * 8 + r) * 64 + lane] = vb16;
                    else
                        unsafeAtomicAdd(&ob[(size_t)s * 64 + lane],
                            __uint_as_float((unsigned)vb16 << 16));
                } else {
                    unsafeAtomicAdd(&ob[(size_t)s * 64 + lane],
                        __uint_as_float((unsigned)vb16 << 16));
                }
            }
        }
    }
}

// 1024 blocks x 4 waves x 8 queries: sum the 8 rank slots per no-tie query
// (coalesced 128B reads) -> out. Tie rows (qflag) already accumulated via
// atomics onto k_pre's zeroed out.
__global__ __launch_bounds__(256) void k_reduce(const unsigned short* __restrict__ Obuf,
                                                const unsigned char* __restrict__ qflag,
                                                float* __restrict__ out) {
    const int wv   = threadIdx.x >> 6;
    const int lane = threadIdx.x & 63;
    const int q0   = (blockIdx.x * 4 + wv) * 8;
    #pragma unroll
    for (int i = 0; i < 8; ++i) {
        int q = q0 + i;
        if (qflag[q]) continue;                // atomic-accumulated row
        const unsigned short* obr = Obuf + (size_t)q * 512;
        float acc = 0.f;
        #pragma unroll
        for (int r = 0; r < 8; ++r)
            acc += __uint_as_float((unsigned)obr[r * 64 + lane] << 16);
        out[(size_t)q * 64 + lane] = acc;
    }
}

extern "C" void kernel_launch(void* const* d_in, const int* in_sizes, int n_in,
                              void* d_out, int out_size, void* d_ws, size_t ws_size,
                              hipStream_t stream) {
    const float* keys    = (const float*)d_in[0];
    const float* values  = (const float*)d_in[1];
    const float* queries = (const float*)d_in[2];
    char* ws = (char*)d_ws;
    int*            kcnt2  = (int*)(ws);
    int*            qcnt2  = (int*)(ws + 262144);
    unsigned short* klist2 = (unsigned short*)(ws + 524288);
    unsigned*       qpair  = (unsigned*)(ws + 4718592);
    unsigned char*  qflag  = (unsigned char*)(ws + 30416896);
    unsigned short* Obuf   = (unsigned short*)(ws + 30449664);
    const bool big2 = (ws_size >= 64004096u);

    k_pre<<<1024, 512, 0, stream>>>(keys, queries, kcnt2, klist2, qcnt2, qpair,
                                    big2 ? qflag : nullptr, (float*)d_out);
    if (big2) {
        k_mainB<true><<<2048, 256, 0, stream>>>(keys, values, queries, kcnt2,
                                                klist2, qcnt2, qpair, Obuf,
                                                (float*)d_out);
        k_reduce<<<1024, 256, 0, stream>>>(Obuf, qflag, (float*)d_out);
    } else {
        k_mainB<false><<<2048, 256, 0, stream>>>(keys, values, queries, kcnt2,
                                                 klist2, qcnt2, qpair, Obuf,
                                                 (float*)d_out);
    }
}

// Round 10
// 130.268 us; speedup vs baseline: 1.1892x; 1.1050x over previous
//
#include <hip/hip_runtime.h>
#include <math.h>

#define S_LEN 1024
#define EPS 1e-6f

typedef __attribute__((ext_vector_type(8)))  short bf16x8;
typedef __attribute__((ext_vector_type(4)))  short bf16x4;
typedef __attribute__((ext_vector_type(16))) float float16v;

// Workspace layout (bytes):
//   kcnt2  : int  [32*64*32]      @ 0          (262144)  [bh][dim][seg]
//   qcnt2  : int  [32*64*32]      @ 262144     (262144)  [bh][dim][seg]
//   klist2 : ushort [2048*1024]   @ 524288     (4194304) [(bh,dim)][seg*32+pos]
//   qpair  : uint [2048*1024]     @ 4718592    (8388608) packed (w18|rank4|s10)
//   --- scatter extension (ws_size >= 64004096) ---
//   qflag  : uchar [32768]        @ 30416896   (32768)   1 = tie row (atomic path)
//   Obuf   : ushort [32768*8*64]  @ 30449664   (33554432) bf16 rank-slot rows
// R10 = R7-verified structure (best, 132.7us). One change: the M-build stages
// ALL <=32 keys of a chunk in ONE parallel round trip into f32 scratch carved
// from dead LDS (Q_bf = k-rows, Ou_bf = v-rows; both dead until the query
// loop), 4 float4 loads/thread. R7 took 2 scalar-load staging iterations +
// 2 barriers for nm~16; this takes 1 wide RT + 1 barrier. R8 (attention-form,
// 42.5KB LDS) and R9 (per-thread serial direct-global loads) both regressed
// and are reverted.

// lgkm-only barrier: __syncthreads() would force vmcnt(0), draining in-flight
// global stores/atomics + prefetch loads. Intra-block hazards here are
// LDS-only; global loads are register-consumed (compiler inserts counted
// vmcnt); stores/atomics are never read back in-kernel.
__device__ __forceinline__ void bar_lgkm() {
    asm volatile("s_waitcnt lgkmcnt(0)" ::: "memory");
    __builtin_amdgcn_s_barrier();
    __builtin_amdgcn_sched_barrier(0);
    asm volatile("" ::: "memory");
}

// VGPR anchor (rule #17): forces materialization at this program point
// (defeats load-sinking; R3 k_pre VGPR=20 showed loads sunk into loops).
#define PIN(x) asm volatile("" : "+v"(x))

__device__ __forceinline__ unsigned short f2bf(float f) {
    unsigned int u = __float_as_uint(f);
    unsigned int r = (u + 0x7fffu + ((u >> 16) & 1u)) >> 16;
    return (unsigned short)r;
}

__device__ __forceinline__ bf16x8 pack8(float4 a, float4 b) {
    bf16x8 r;
    r[0] = (short)f2bf(a.x); r[1] = (short)f2bf(a.y);
    r[2] = (short)f2bf(a.z); r[3] = (short)f2bf(a.w);
    r[4] = (short)f2bf(b.x); r[5] = (short)f2bf(b.y);
    r[6] = (short)f2bf(b.z); r[7] = (short)f2bf(b.w);
    return r;
}

// 1024 blocks = (bh, seg), 512 threads = 8 waves x 4 positions. (R7 verbatim)
__global__ __launch_bounds__(512) void k_pre(const float* __restrict__ keys,
                                             const float* __restrict__ queries,
                                             int* __restrict__ kcnt2,
                                             unsigned short* __restrict__ klist2,
                                             int* __restrict__ qcnt2,
                                             unsigned* __restrict__ qpair,
                                             unsigned char* __restrict__ qflag,
                                             float* __restrict__ out) {
    const int bh   = blockIdx.x >> 5;
    const int blk  = blockIdx.x & 31;          // segment id
    const int wv   = threadIdx.x >> 6;         // 0..7
    const int lane = threadIdx.x & 63;

    __shared__ int khist[64], qhist[64];
    __shared__ alignas(16) unsigned rq_s[8][4][64];   // 8 KB: per-wave row stage
    if (threadIdx.x < 64) { khist[threadIdx.x] = 0; qhist[threadIdx.x] = 0; }
    __syncthreads();

    const int s0 = blk * 32 + wv * 4;
    float kv[4], qv[4];
    #pragma unroll
    for (int i = 0; i < 4; ++i) {              // all loads issued up-front
        kv[i] = keys   [((size_t)bh * 1024 + s0 + i) * 64 + lane];
        qv[i] = queries[((size_t)bh * 1024 + s0 + i) * 64 + lane];
    }

    // zero d_out slice (independent store, issues inside the load shadow)
    {
        float4 zz = {0.f, 0.f, 0.f, 0.f};
        float4* po = (float4*)(out + (size_t)blockIdx.x * 2048);
        po[threadIdx.x] = zz;
    }

    // anchor: one vmcnt wait for all 8 loads; compute below is register/LDS
    #pragma unroll
    for (int i = 0; i < 4; ++i) { PIN(kv[i]); PIN(qv[i]); }

    // stage |q| bits to LDS (wave-private rows)
    unsigned ud[4];
    #pragma unroll
    for (int i = 0; i < 4; ++i) {
        ud[i] = __float_as_uint(qv[i]) & 0x7fffffffu;
        rq_s[wv][i][lane] = ud[i];
    }

    // ---- keys: 4 interleaved wave-argmaxes ----
    float bv[4]; int bi[4];
    #pragma unroll
    for (int i = 0; i < 4; ++i) { bv[i] = fabsf(kv[i]); bi[i] = lane; }
    #pragma unroll
    for (int off = 1; off < 64; off <<= 1) {
        #pragma unroll
        for (int i = 0; i < 4; ++i) {
            float ov = __shfl_xor(bv[i], off, 64);
            int   oi = __shfl_xor(bi[i], off, 64);
            if (ov > bv[i] || (ov == bv[i] && oi < bi[i])) { bv[i] = ov; bi[i] = oi; }
        }
    }
    #pragma unroll
    for (int i = 0; i < 4; ++i) {
        if (lane == 0) {
            int pos = atomicAdd(&khist[bi[i]], 1);
            klist2[((size_t)bh * 64 + bi[i]) * 1024 + blk * 32 + pos] =
                (unsigned short)(s0 + i);
        }
    }

    // ---- queries: rank via LDS uint4 broadcast (same-addr, conflict-free) ----
    int gt[4] = {0, 0, 0, 0};
    #pragma unroll
    for (int k4 = 0; k4 < 16; ++k4) {
        #pragma unroll
        for (int i = 0; i < 4; ++i) {
            const uint4 vv = *(const uint4*)&rq_s[wv][i][k4 * 4];
            gt[i] += (vv.x > ud[i]) ? 1 : 0;
            gt[i] += (vv.y > ud[i]) ? 1 : 0;
            gt[i] += (vv.z > ud[i]) ? 1 : 0;
            gt[i] += (vv.w > ud[i]) ? 1 : 0;
        }
    }
    int S[4];                                  // permutation check for ties
    #pragma unroll
    for (int i = 0; i < 4; ++i) S[i] = gt[i];
    #pragma unroll
    for (int off = 1; off < 64; off <<= 1) {
        #pragma unroll
        for (int i = 0; i < 4; ++i) S[i] += __shfl_xor(S[i], off, 64);
    }
    float e[4];
    #pragma unroll
    for (int i = 0; i < 4; ++i) e[i] = expf(__uint_as_float(ud[i]));
    int copies[4], contrib[4], rank[4];
    #pragma unroll
    for (int i = 0; i < 4; ++i) {
        if (S[i] == 2016) {                    // no ties (wave-uniform branch)
            contrib[i] = (gt[i] < 8);
            copies[i]  = contrib[i] ? 2 : 0;
            rank[i]    = gt[i];                // unique slot 0..7
        } else {                               // exact tie handling (rare)
            int eq = 0, eql = 0;
            #pragma unroll
            for (int k = 0; k < 64; ++k) {
                unsigned ui = (unsigned)__builtin_amdgcn_readlane((int)ud[i], k);
                eq  += (ui == ud[i]) ? 1 : 0;
                eql += (ui == ud[i] && k < lane) ? 1 : 0;
            }
            int pos_low  = 2 * gt[i] + eql;
            int pos_high = pos_low + eq;       // eq includes self
            copies[i]  = (pos_low < 16 ? 1 : 0) + (pos_high < 16 ? 1 : 0);
            contrib[i] = (pos_low < 16);
            rank[i]    = 15;                   // sentinel -> atomic path
        }
    }
    float ce[4];
    #pragma unroll
    for (int i = 0; i < 4; ++i) ce[i] = (float)copies[i] * e[i];
    #pragma unroll
    for (int off = 1; off < 64; off <<= 1) {
        #pragma unroll
        for (int i = 0; i < 4; ++i) ce[i] += __shfl_xor(ce[i], off, 64);
    }
    #pragma unroll
    for (int i = 0; i < 4; ++i) {
        if (contrib[i]) {
            int pos = atomicAdd(&qhist[lane], 1);
            unsigned wb = __float_as_uint(e[i] / ce[i]) & 0xFFFFC000u;  // 18-bit w
            qpair[((size_t)bh * 64 + lane) * 1024 + blk * 32 + pos] =
                wb | ((unsigned)rank[i] << 10) | (unsigned)(s0 + i);
        }
        if (qflag && lane == 0)
            qflag[bh * 1024 + s0 + i] = (S[i] == 2016) ? 0 : 1;
    }
    __syncthreads();
    if (threadIdx.x < 64) {                    // transposed [bh][dim][seg]
        kcnt2[(bh * 64 + threadIdx.x) * 32 + blk] = khist[threadIdx.x];
        qcnt2[(bh * 64 + threadIdx.x) * 32 + blk] = qhist[threadIdx.x];
    }
}

// 2048 blocks = (bh, bank), fused build + query (R7 structure). R10: build
// stages a whole 32-key chunk at once (1 parallel RT, 1 barrier) into f32
// scratch aliased onto Q_bf (k) and Ou_bf (v), which are dead until the
// query loop. SC: flush -> rank-addressed Obuf slots (plain stores);
// rank-15 ties -> atomics; k_reduce sums.
template <bool SC>
__global__ __launch_bounds__(256) void k_mainB(const float* __restrict__ keys,
                                               const float* __restrict__ values,
                                               const float* __restrict__ queries,
                                               const int* __restrict__ kcnt2,
                                               const unsigned short* __restrict__ klist2,
                                               const int* __restrict__ qcnt2,
                                               const unsigned* __restrict__ qpair,
                                               unsigned short* __restrict__ Obuf,
                                               float* __restrict__ out) {
    const int g     = blockIdx.x;      // 0..2047 = (bh, bank)
    const int bh    = g >> 6;
    const int bank  = g & 63;
    const int t     = threadIdx.x;
    const int lane  = t & 63;
    const int grp   = t >> 6;

    __shared__ alignas(16) unsigned short M_bf[64 * 64];   // 8 KB
    __shared__ alignas(16) unsigned short Q_bf[64 * 64];   // 8 KB (build: k-scratch f32)
    __shared__ alignas(16) unsigned short Ou_bf[64 * 68];  // 8.7 KB (build: v-scratch f32)
    __shared__ unsigned short s_match[256];
    __shared__ unsigned q_ent[256];
    __shared__ int    koffs_s[33], qoffs_s[33];
    __shared__ float  z_s[64];
    __shared__ double den_s[64];
    __shared__ float  w_s[2][64];
    __shared__ int    sq_s[2][64];

    // dual prefix scan: lanes 0-31 keys, 32-63 queries (contiguous counts)
    if (t < 64) {
        int i = t & 31;
        int c = (t < 32) ? kcnt2[(bh * 64 + bank) * 32 + i]
                         : qcnt2[(bh * 64 + bank) * 32 + i];
        #pragma unroll
        for (int off = 1; off < 32; off <<= 1) {
            int o = __shfl(c, t - off, 64);    // guarded by i >= off
            if (i >= off) c += o;
        }
        if (t < 32) { if (i == 0) koffs_s[0] = 0; koffs_s[i + 1] = c; }
        else        { if (i == 0) qoffs_s[0] = 0; qoffs_s[i + 1] = c; }
    }
    bar_lgkm();

    const int nq = qoffs_s[32];
    const int nm = koffs_s[32];
    if (nq == 0) return;
    const size_t listbase = (size_t)(bh * 64 + bank) * 1024;
    if (nm == 0) {
        // SC: empty bank still owns Obuf slots for its entries -> zero-fill
        if constexpr (SC) {
            for (int jg = t; jg < nq; jg += 256) {
                int seg = 0;
                #pragma unroll
                for (int i = 1; i < 32; ++i) if (jg >= qoffs_s[i]) seg = i;
                unsigned e = qpair[listbase + seg * 32 + (jg - qoffs_s[seg])];
                int r = (e >> 10) & 15;
                if (r < 8) {
                    uint4 z4 = {0u, 0u, 0u, 0u};
                    uint4* dst = (uint4*)&Obuf[(((size_t)bh * 1024 +
                                 (e & 1023u)) * 8 + r) * 64];
                    #pragma unroll
                    for (int x = 0; x < 8; ++x) dst[x] = z4;
                }
            }
        }
        return;
    }

    // ---- phase 2: both chunk-0 gathers issued together (one bar) ----
    {
        if (t < min(256, nm)) {                // klist chunk 0
            int seg = 0;
            #pragma unroll
            for (int i = 1; i < 32; ++i) if (t >= koffs_s[i]) seg = i;
            s_match[t] = klist2[listbase + seg * 32 + (t - koffs_s[seg])];
        }
        if (t < min(256, nq)) {                // q_ent chunk 0 (hides under build)
            int seg = 0;
            #pragma unroll
            for (int i = 1; i < 32; ++i) if (t >= qoffs_s[i]) seg = i;
            q_ent[t] = qpair[listbase + seg * 32 + (t - qoffs_s[seg])];
        }
    }
    bar_lgkm();

    // ---- build M[dv][dk] = sum_s v[s][dv]*k[s][dk], z[dk] = sum_s k[s][dk]
    // R10: whole 32-key chunk staged at once -> 1 parallel RT + 1 barrier.
    //   thread t: row r = t>>3, col-octet c8 = t&7 (2 float4 each of k and v)
    {
        float* kstf = (float*)Q_bf;            // 32x64 f32 = 8 KB (Q_bf dead)
        float* vstf = (float*)Ou_bf;           // 32x64 f32 = 8 KB (Ou_bf dead)
        float acc[16];
        #pragma unroll
        for (int m = 0; m < 16; ++m) acc[m] = 0.f;
        float zacc = 0.f;
        const float* kb = keys   + (size_t)bh * S_LEN * 64;
        const float* vb = values + (size_t)bh * S_LEN * 64;
        int win = 0;                           // s_match window base
        for (int cb = 0; cb < nm; cb += 32) {
            const int cn = min(32, nm - cb);
            if ((cb & ~255) != win) {          // refill window (nm>256: ~never)
                bar_lgkm();
                win = cb & ~255;
                int wn = min(256, nm - win);
                if (t < wn) {
                    int idx = win + t, seg = 0;
                    #pragma unroll
                    for (int i = 1; i < 32; ++i) if (idx >= koffs_s[i]) seg = i;
                    s_match[t] = klist2[listbase + seg * 32 + (idx - koffs_s[seg])];
                }
                bar_lgkm();
            }
            if (cb > 0) bar_lgkm();            // prev chunk's scratch reads done
            {
                int r = t >> 3, c8 = t & 7;
                if (r < cn) {
                    int s = s_match[(cb - win) + r];
                    const float4* ks = (const float4*)(kb + (size_t)s * 64 + c8 * 8);
                    float4 k0 = ks[0], k1 = ks[1];
                    const float4* vs = (const float4*)(vb + (size_t)s * 64 + c8 * 8);
                    float4 w0 = vs[0], w1 = vs[1];
                    float4* kd = (float4*)&kstf[r * 64 + c8 * 8];
                    kd[0] = k0; kd[1] = k1;
                    float4* vd = (float4*)&vstf[r * 64 + c8 * 8];
                    vd[0] = w0; vd[1] = w1;
                }
            }
            bar_lgkm();                        // staging visible (1 barrier/chunk)
            for (int r = 0; r < cn; ++r) {
                float kv = kstf[r * 64 + lane];        // dk = lane (coalesced)
                #pragma unroll
                for (int m = 0; m < 16; ++m)           // dv = grp*16+m (broadcast)
                    acc[m] += vstf[r * 64 + grp * 16 + m] * kv;
            }
            if (t < 64)
                for (int r = 0; r < cn; ++r) zacc += kstf[r * 64 + t];
        }
        // write M as bf16, row-major [dv][dk], 16B-chunk XOR swizzle
        #pragma unroll
        for (int m = 0; m < 16; ++m) {
            int dv = grp * 16 + m;
            M_bf[dv * 64 + (((lane >> 3) ^ (dv & 7)) << 3) + (lane & 7)] = f2bf(acc[m]);
        }
        if (t < 64) z_s[t] = zacc;
    }
    bar_lgkm();                        // M_bf/z_s visible; scratch reads done

    // ---- query loop over [0, nq): pipelined + prefetched (R7 verbatim) ----
    const float* qb = queries + (size_t)bh * S_LEN * 64;
    float*       ob = out     + (size_t)bh * S_LEN * 64;
    unsigned short* obuf_b = SC ? Obuf + (size_t)bh * 1024 * 512 : nullptr;
    const int dvh = grp >> 1, jh = grp & 1;            // wave's 32x32 tile
    const int hi  = lane >> 5;
    const int jq  = t >> 2, cq = t & 3;                // stage mapping

    int prev_nb = 0;
    bool have_pf = false;                              // next-batch q row in regs
    float4 f0, f1, f2, f3;
    unsigned pe = 0;
    for (int qloc = 0, batch = 0; qloc < nq; qloc += 64, ++batch) {
        const int nb  = min(64, nq - qloc);
        const int cur = batch & 1;

        if (qloc != 0 && (qloc & 255) == 0) {  // refill q_ent past chunk 0
            if (qloc + t < nq) {
                int jg = qloc + t;
                int seg = 0;
                #pragma unroll
                for (int i = 1; i < 32; ++i) if (jg >= qoffs_s[i]) seg = i;
                q_ent[t] = qpair[listbase + seg * 32 + (jg - qoffs_s[seg])];
            }
            bar_lgkm();
        }

        // A1: entry + cold q loads issued FIRST (don't queue behind stores)
        unsigned e = 0;
        const bool act = (jq < nb);
        if (act) {
            e = have_pf ? pe : q_ent[(qloc & 255) + jq];
            if (!have_pf) {
                const float4* src =
                    (const float4*)(qb + (size_t)(e & 1023u) * 64 + cq * 16);
                f0 = src[0]; f1 = src[1]; f2 = src[2]; f3 = src[3];
            }
        }

        // A2: flush previous batch (SC: plain bf16 stores to rank slots;
        // rank-15 tie entries keep atomic add; fire-and-forget either way)
        if (batch > 0) {
            #pragma unroll
            for (int jj = 0; jj < 16; ++jj) {
                int j = grp * 16 + jj;
                if (j < prev_nb) {
                    unsigned short vb16 = Ou_bf[j * 68 + lane];
                    int sr = sq_s[1 - cur][j];
                    int s  = sr & 1023;
                    if constexpr (SC) {
                        int r = (sr >> 10) & 15;
                        if (r < 8)
                            obuf_b[((size_t)s * 8 + r) * 64 + lane] = vb16;
                        else
                            unsafeAtomicAdd(&ob[(size_t)s * 64 + lane],
                                __uint_as_float((unsigned)vb16 << 16));
                    } else {
                        unsafeAtomicAdd(&ob[(size_t)s * 64 + lane],
                            __uint_as_float((unsigned)vb16 << 16));
                    }
                }
            }
        }

        // A3: pack + denominator + LDS stage
        {
            bf16x8 p0 = {}, p1 = {};
            double d = 0.0;
            if (act) {
                if ((t & 3) == 0) {
                    sq_s[cur][jq] = (int)(e & 0x3FFFu);        // s | rank<<10
                    w_s[cur][jq]  = __uint_as_float(e & 0xFFFFC000u);
                }
                p0 = pack8(f0, f1);
                p1 = pack8(f2, f3);
                const float4* zz4 = (const float4*)&z_s[cq * 16];
                float4 z0 = zz4[0], z1 = zz4[1], z2 = zz4[2], z3 = zz4[3];
                double da, db;
                da  = (double)z0.x * f0.x + (double)z0.y * f0.y + (double)z0.z * f0.z + (double)z0.w * f0.w;
                db  = (double)z1.x * f1.x + (double)z1.y * f1.y + (double)z1.z * f1.z + (double)z1.w * f1.w;
                da += (double)z2.x * f2.x + (double)z2.y * f2.y + (double)z2.z * f2.z + (double)z2.w * f2.w;
                db += (double)z3.x * f3.x + (double)z3.y * f3.y + (double)z3.z * f3.z + (double)z3.w * f3.w;
                d = da + db;
            }
            int c0 = cq * 2;
            *(bf16x8*)&Q_bf[jq * 64 + ((c0 ^ (jq & 7)) << 3)]       = p0;
            *(bf16x8*)&Q_bf[jq * 64 + (((c0 + 1) ^ (jq & 7)) << 3)] = p1;
            d += __shfl_xor(d, 1, 64);
            d += __shfl_xor(d, 2, 64);
            if ((t & 3) == 0) den_s[jq] = d;
        }

        // A4: prefetch next batch's q row into registers (same chunk only)
        {
            const int qn = qloc + 64;
            have_pf = false;
            if (qn < nq && (qn & 255) != 0) {
                int nbn = min(64, nq - qn);
                if (jq < nbn) {
                    pe = q_ent[(qn & 255) + jq];
                    const float4* src =
                        (const float4*)(qb + (size_t)(pe & 1023u) * 64 + cq * 16);
                    f0 = src[0]; f1 = src[1]; f2 = src[2]; f3 = src[3];
                    have_pf = true;
                }
            }
        }
        bar_lgkm();                    // (C) staged; prev Ou_bf reads complete

        // MFMA: O[dv][j] = sum_dk M[dv][dk] * Q[j][dk]
        float16v C;
        #pragma unroll
        for (int i = 0; i < 16; ++i) C[i] = 0.f;
        const int am = dvh * 32 + (lane & 31);
        const int bn = jh  * 32 + (lane & 31);
        #pragma unroll
        for (int ks = 0; ks < 4; ++ks) {
            int ch = ks * 2 + hi;
            bf16x8 af = *(const bf16x8*)&M_bf[am * 64 + ((ch ^ (am & 7)) << 3)];
            bf16x8 bf = *(const bf16x8*)&Q_bf[bn * 64 + ((ch ^ (bn & 7)) << 3)];
            C = __builtin_amdgcn_mfma_f32_32x32x16_bf16(af, bf, C, 0, 0, 0);
        }
        // epilogue: scale by w/den, write O^T[j=bn][dv] as bf16
        {
            double den = den_s[bn];
            float  w   = w_s[cur][bn];
            float rinv = (float)((double)w / (den + (double)EPS));
            #pragma unroll
            for (int rq = 0; rq < 4; ++rq) {
                bf16x4 pk;
                pk[0] = (short)f2bf(C[rq * 4 + 0] * rinv);
                pk[1] = (short)f2bf(C[rq * 4 + 1] * rinv);
                pk[2] = (short)f2bf(C[rq * 4 + 2] * rinv);
                pk[3] = (short)f2bf(C[rq * 4 + 3] * rinv);
                *(bf16x4*)&Ou_bf[bn * 68 + dvh * 32 + rq * 8 + hi * 4] = pk;
            }
        }
        bar_lgkm();                    // (D) O ready; Q_bf reads complete
        prev_nb = nb;
    }
    // final flush
    {
        const int cur = (((nq + 63) >> 6) - 1) & 1;    // parity of last batch
        #pragma unroll
        for (int jj = 0; jj < 16; ++jj) {
            int j = grp * 16 + jj;
            if (j < prev_nb) {
                unsigned short vb16 = Ou_bf[j * 68 + lane];
                int sr = sq_s[cur][j];
                int s  = sr & 1023;
                if constexpr (SC) {
                    int r = (sr >> 10) & 15;
                    if (r < 8)
                        obuf_b[((size_t)s * 8 + r) * 64 + lane] = vb16;
                    else
                        unsafeAtomicAdd(&ob[(size_t)s * 64 + lane],
                            __uint_as_float((unsigned)vb16 << 16));
                } else {
                    unsafeAtomicAdd(&ob[(size_t)s * 64 + lane],
                        __uint_as_float((unsigned)vb16 << 16));
                }
            }
        }
    }
}

// 1024 blocks x 4 waves x 8 queries: sum the 8 rank slots per no-tie query
// (coalesced 128B reads) -> out. Tie rows (qflag) already accumulated via
// atomics onto k_pre's zeroed out.
__global__ __launch_bounds__(256) void k_reduce(const unsigned short* __restrict__ Obuf,
                                                const unsigned char* __restrict__ qflag,
                                                float* __restrict__ out) {
    const int wv   = threadIdx.x >> 6;
    const int lane = threadIdx.x & 63;
    const int q0   = (blockIdx.x * 4 + wv) * 8;
    #pragma unroll
    for (int i = 0; i < 8; ++i) {
        int q = q0 + i;
        if (qflag[q]) continue;                // atomic-accumulated row
        const unsigned short* obr = Obuf + (size_t)q * 512;
        float acc = 0.f;
        #pragma unroll
        for (int r = 0; r < 8; ++r)
            acc += __uint_as_float((unsigned)obr[r * 64 + lane] << 16);
        out[(size_t)q * 64 + lane] = acc;
    }
}

extern "C" void kernel_launch(void* const* d_in, const int* in_sizes, int n_in,
                              void* d_out, int out_size, void* d_ws, size_t ws_size,
                              hipStream_t stream) {
    const float* keys    = (const float*)d_in[0];
    const float* values  = (const float*)d_in[1];
    const float* queries = (const float*)d_in[2];
    char* ws = (char*)d_ws;
    int*            kcnt2  = (int*)(ws);
    int*            qcnt2  = (int*)(ws + 262144);
    unsigned short* klist2 = (unsigned short*)(ws + 524288);
    unsigned*       qpair  = (unsigned*)(ws + 4718592);
    unsigned char*  qflag  = (unsigned char*)(ws + 30416896);
    unsigned short* Obuf   = (unsigned short*)(ws + 30449664);
    const bool big2 = (ws_size >= 64004096u);

    k_pre<<<1024, 512, 0, stream>>>(keys, queries, kcnt2, klist2, qcnt2, qpair,
                                    big2 ? qflag : nullptr, (float*)d_out);
    if (big2) {
        k_mainB<true><<<2048, 256, 0, stream>>>(keys, values, queries, kcnt2,
                                                klist2, qcnt2, qpair, Obuf,
                                                (float*)d_out);
        k_reduce<<<1024, 256, 0, stream>>>(Obuf, qflag, (float*)d_out);
    } else {
        k_mainB<false><<<2048, 256, 0, stream>>>(keys, values, queries, kcnt2,
                                                 klist2, qcnt2, qpair, Obuf,
                                                 (float*)d_out);
    }
}